// Round 1
// baseline (876.219 us; speedup 1.0000x reference)
//
#include <hip/hip_runtime.h>

#define NTOK 4096
#define DIN  4096
#define DOUT 4096

typedef short bf16x8 __attribute__((ext_vector_type(8)));
typedef float f32x4  __attribute__((ext_vector_type(4)));

__device__ __forceinline__ unsigned short f2bf(float f) {
    union { float f; unsigned u; } v; v.f = f;
    unsigned r = v.u + 0x7FFFu + ((v.u >> 16) & 1u);
    return (unsigned short)(r >> 16);
}

// ---------------- per-row scale (fp64 for quantization-boundary fidelity) ----------------
__global__ void scale_kernel(const float* __restrict__ w, double* __restrict__ scale) {
    int row = blockIdx.x;
    const float4* wr = (const float4*)(w + (size_t)row * DIN);
    double s = 0.0;
    for (int i = threadIdx.x; i < DIN / 4; i += 256) {
        float4 v = wr[i];
        s += (double)fabsf(v.x) + (double)fabsf(v.y) + (double)fabsf(v.z) + (double)fabsf(v.w);
    }
    for (int o = 32; o > 0; o >>= 1) s += __shfl_down(s, o);
    __shared__ double part[4];
    int wave = threadIdx.x >> 6, lane = threadIdx.x & 63;
    if (lane == 0) part[wave] = s;
    __syncthreads();
    if (threadIdx.x == 0) {
        double m = (part[0] + part[1] + part[2] + part[3]) * (1.0 / DIN);
        scale[row] = fmax(m, 1e-5);
    }
}

// ---------------- build w_eff bf16 ----------------
__global__ void weff_kernel(const float* __restrict__ w, const float* __restrict__ fast,
                            const float* __restrict__ slow, const double* __restrict__ scale,
                            unsigned short* __restrict__ weff) {
    int i4 = blockIdx.x * 256 + threadIdx.x;   // float4 index, 4194304 total
    double sc = scale[i4 >> 10];
    float4 wv = ((const float4*)w)[i4];
    float4 fv = ((const float4*)fast)[i4];
    float4 sv = ((const float4*)slow)[i4];
    ushort4 o;
    o.x = f2bf((float)(fmin(fmax(rint((double)wv.x / sc), -1.0), 1.0) * sc + 0.1 * (double)fv.x + 0.05 * (double)sv.x));
    o.y = f2bf((float)(fmin(fmax(rint((double)wv.y / sc), -1.0), 1.0) * sc + 0.1 * (double)fv.y + 0.05 * (double)sv.y));
    o.z = f2bf((float)(fmin(fmax(rint((double)wv.z / sc), -1.0), 1.0) * sc + 0.1 * (double)fv.z + 0.05 * (double)sv.z));
    o.w = f2bf((float)(fmin(fmax(rint((double)wv.w / sc), -1.0), 1.0) * sc + 0.1 * (double)fv.w + 0.05 * (double)sv.w));
    ((ushort4*)weff)[i4] = o;
}

// ---------------- x -> xT bf16 ----------------
__global__ void transpose_kernel(const float* __restrict__ x, unsigned short* __restrict__ xT) {
    __shared__ unsigned short tile[32][33];
    int bi = blockIdx.y, bj = blockIdx.x;
    int tx = threadIdx.x, ty = threadIdx.y;  // (32, 8)
    #pragma unroll
    for (int s = 0; s < 4; ++s)
        tile[ty + s * 8][tx] = f2bf(x[(size_t)(bi * 32 + ty + s * 8) * DIN + bj * 32 + tx]);
    __syncthreads();
    #pragma unroll
    for (int s = 0; s < 4; ++s)
        xT[(size_t)(bj * 32 + ty + s * 8) * NTOK + bi * 32 + tx] = tile[tx][ty + s * 8];
}

// ---------------- GEMM1: y[n,m] = sum_k x[n,k]*weff[m,k]; epilogue: y fp32 + relu(y)^T bf16 ----------------
__launch_bounds__(256)
__global__ void gemm1_kernel(const float* __restrict__ x, const unsigned short* __restrict__ weff,
                             float* __restrict__ y, unsigned short* __restrict__ yactT) {
    __shared__ unsigned short smem[16640];           // 33.3 KB: staging (16KB) then 128x130 transpose
    unsigned short* sA = smem;                       // [128][32]
    unsigned short* sB = smem + 4096;                // [128][32]
    int tid = threadIdx.x;
    int wave = tid >> 6, lane = tid & 63, quad = lane >> 4, l16 = lane & 15;
    int waveRow = wave >> 1, waveCol = wave & 1;
    int rowBase = blockIdx.y * 128;                  // n
    int colBase = blockIdx.x * 128;                  // m

    f32x4 zero = {0.f, 0.f, 0.f, 0.f};
    f32x4 acc[4][4];
    #pragma unroll
    for (int i = 0; i < 4; ++i)
        #pragma unroll
        for (int j = 0; j < 4; ++j) acc[i][j] = zero;

    for (int k0 = 0; k0 < DIN; k0 += 32) {
        #pragma unroll
        for (int p = 0; p < 4; ++p) {                // A: x fp32 -> bf16, 1024 float4 chunks
            int c = tid + p * 256;
            int r = c >> 3, kk = (c & 7) * 4;
            float4 v = *(const float4*)(x + (size_t)(rowBase + r) * DIN + k0 + kk);
            ushort4 o = { f2bf(v.x), f2bf(v.y), f2bf(v.z), f2bf(v.w) };
            *(ushort4*)(sA + r * 32 + kk) = o;
        }
        #pragma unroll
        for (int p = 0; p < 2; ++p) {                // B: weff bf16, 512 uint4 chunks
            int c = tid + p * 256;
            int r = c >> 2, kk = (c & 3) * 8;
            uint4 v = *(const uint4*)(weff + (size_t)(colBase + r) * DIN + k0 + kk);
            *(uint4*)(sB + r * 32 + kk) = v;
        }
        __syncthreads();
        bf16x8 af[4], bfr[4];
        #pragma unroll
        for (int i = 0; i < 4; ++i)
            af[i] = *(const bf16x8*)(sA + (waveRow * 64 + i * 16 + l16) * 32 + quad * 8);
        #pragma unroll
        for (int j = 0; j < 4; ++j)
            bfr[j] = *(const bf16x8*)(sB + (waveCol * 64 + j * 16 + l16) * 32 + quad * 8);
        #pragma unroll
        for (int i = 0; i < 4; ++i)
            #pragma unroll
            for (int j = 0; j < 4; ++j)
                acc[i][j] = __builtin_amdgcn_mfma_f32_16x16x32_bf16(af[i], bfr[j], acc[i][j], 0, 0, 0);
        __syncthreads();
    }

    // y fp32 store + relu-transpose into LDS
    #pragma unroll
    for (int i = 0; i < 4; ++i) {
        int rl = waveRow * 64 + i * 16 + quad * 4;
        #pragma unroll
        for (int j = 0; j < 4; ++j) {
            int cl = waveCol * 64 + j * 16 + l16;
            #pragma unroll
            for (int r = 0; r < 4; ++r) {
                float v = acc[i][j][r];
                y[(size_t)(rowBase + rl + r) * DOUT + colBase + cl] = v;
                smem[cl * 130 + rl + r] = f2bf(fmaxf(v, 0.0f));
            }
        }
    }
    __syncthreads();
    // coalesced write of yactT[m][n]
    int rowT = tid >> 1, cst = (tid & 1) * 64;
    const unsigned int* l32 = (const unsigned int*)smem;
    int b2 = rowT * 65 + (cst >> 1);
    #pragma unroll
    for (int g = 0; g < 8; ++g) {
        uint4 v;
        v.x = l32[b2 + g * 4 + 0]; v.y = l32[b2 + g * 4 + 1];
        v.z = l32[b2 + g * 4 + 2]; v.w = l32[b2 + g * 4 + 3];
        *(uint4*)(yactT + (size_t)(colBase + rowT) * NTOK + rowBase + cst + g * 8) = v;
    }
}

// ---------------- GEMM2: nf_pre[m,k] = 0.95*fast + 0.05*(sum_n yactT[m,n]*xT[k,n])/4096 ----------------
__launch_bounds__(256)
__global__ void gemm2_kernel(const unsigned short* __restrict__ yactT, const unsigned short* __restrict__ xT,
                             const float* __restrict__ fast, float* __restrict__ outFast,
                             float* __restrict__ norm2) {
    __shared__ unsigned short sA[128 * 32];
    __shared__ unsigned short sB[128 * 32];
    __shared__ float redbuf[4];
    int tid = threadIdx.x;
    int wave = tid >> 6, lane = tid & 63, quad = lane >> 4, l16 = lane & 15;
    int waveRow = wave >> 1, waveCol = wave & 1;
    int rowBase = blockIdx.y * 128;                  // m
    int colBase = blockIdx.x * 128;                  // k

    f32x4 zero = {0.f, 0.f, 0.f, 0.f};
    f32x4 acc[4][4];
    #pragma unroll
    for (int i = 0; i < 4; ++i)
        #pragma unroll
        for (int j = 0; j < 4; ++j) acc[i][j] = zero;

    for (int n0 = 0; n0 < NTOK; n0 += 32) {
        #pragma unroll
        for (int p = 0; p < 2; ++p) {
            int c = tid + p * 256;
            int r = c >> 2, nn = (c & 3) * 8;
            uint4 va = *(const uint4*)(yactT + (size_t)(rowBase + r) * NTOK + n0 + nn);
            *(uint4*)(sA + r * 32 + nn) = va;
            uint4 vb = *(const uint4*)(xT + (size_t)(colBase + r) * NTOK + n0 + nn);
            *(uint4*)(sB + r * 32 + nn) = vb;
        }
        __syncthreads();
        bf16x8 af[4], bfr[4];
        #pragma unroll
        for (int i = 0; i < 4; ++i)
            af[i] = *(const bf16x8*)(sA + (waveRow * 64 + i * 16 + l16) * 32 + quad * 8);
        #pragma unroll
        for (int j = 0; j < 4; ++j)
            bfr[j] = *(const bf16x8*)(sB + (waveCol * 64 + j * 16 + l16) * 32 + quad * 8);
        #pragma unroll
        for (int i = 0; i < 4; ++i)
            #pragma unroll
            for (int j = 0; j < 4; ++j)
                acc[i][j] = __builtin_amdgcn_mfma_f32_16x16x32_bf16(af[i], bfr[j], acc[i][j], 0, 0, 0);
        __syncthreads();
    }

    float lsum = 0.f;
    #pragma unroll
    for (int i = 0; i < 4; ++i) {
        int rg = rowBase + waveRow * 64 + i * 16 + quad * 4;
        #pragma unroll
        for (int j = 0; j < 4; ++j) {
            int cg = colBase + waveCol * 64 + j * 16 + l16;
            #pragma unroll
            for (int r = 0; r < 4; ++r) {
                float d = acc[i][j][r] * (1.0f / 4096.0f);
                float nf = 0.95f * fast[(size_t)(rg + r) * DIN + cg] + 0.05f * d;
                outFast[(size_t)(rg + r) * DIN + cg] = nf;
                lsum += nf * nf;
            }
        }
    }
    for (int o = 32; o > 0; o >>= 1) lsum += __shfl_down(lsum, o);
    if (lane == 0) redbuf[wave] = lsum;
    __syncthreads();
    if (tid == 0) atomicAdd(norm2, redbuf[0] + redbuf[1] + redbuf[2] + redbuf[3]);
}

// ---------------- finalize: homeostatic rescale + slow update ----------------
__global__ void finalize_kernel(const float* __restrict__ slow, float* __restrict__ outFast,
                                float* __restrict__ outSlow, const float* __restrict__ norm2) {
    float n = sqrtf(*norm2);
    float s = (n > 5.0f) ? 5.0f / (n + 1e-6f) : 1.0f;
    int i = blockIdx.x * 256 + threadIdx.x;          // float4 index
    float4 f = ((const float4*)outFast)[i];
    f.x *= s; f.y *= s; f.z *= s; f.w *= s;
    ((float4*)outFast)[i] = f;
    float4 sl = ((const float4*)slow)[i];
    float4 o;
    o.x = 0.99f * sl.x + 0.01f * f.x;
    o.y = 0.99f * sl.y + 0.01f * f.y;
    o.z = 0.99f * sl.z + 0.01f * f.z;
    o.w = 0.99f * sl.w + 0.01f * f.w;
    ((float4*)outSlow)[i] = o;
}

extern "C" void kernel_launch(void* const* d_in, const int* in_sizes, int n_in,
                              void* d_out, int out_size, void* d_ws, size_t ws_size,
                              hipStream_t stream) {
    const float* x    = (const float*)d_in[0];
    const float* w    = (const float*)d_in[1];
    const float* fast = (const float*)d_in[2];
    const float* slow = (const float*)d_in[3];
    float* y       = (float*)d_out;
    float* outFast = y + (size_t)NTOK * DOUT;
    float* outSlow = outFast + (size_t)DOUT * DIN;

    char* ws = (char*)d_ws;
    double* scale = (double*)ws;                               // 32 KB
    float* norm2  = (float*)(ws + 32768);                      // 4 B (+pad)
    unsigned short* weff  = (unsigned short*)(ws + 32768 + 256);
    unsigned short* xT    = weff + (size_t)DOUT * DIN;
    unsigned short* yactT = xT + (size_t)DIN * NTOK;
    // total ws use: ~33 KB + 3 * 33.55 MB ≈ 100.7 MB

    hipMemsetAsync(norm2, 0, sizeof(float), stream);
    scale_kernel<<<4096, 256, 0, stream>>>(w, scale);
    weff_kernel<<<16384, 256, 0, stream>>>(w, fast, slow, scale, weff);
    transpose_kernel<<<dim3(128, 128), dim3(32, 8), 0, stream>>>(x, xT);
    gemm1_kernel<<<dim3(32, 32), 256, 0, stream>>>(x, weff, y, yactT);
    gemm2_kernel<<<dim3(32, 32), 256, 0, stream>>>(yactT, xT, fast, outFast, norm2);
    finalize_kernel<<<16384, 256, 0, stream>>>(slow, outFast, outSlow, norm2);
}

// Round 2
// 813.923 us; speedup vs baseline: 1.0765x; 1.0765x over previous
//
#include <hip/hip_runtime.h>

#define NTOK 4096
#define DIN  4096
#define DOUT 4096

typedef short bf16x8 __attribute__((ext_vector_type(8)));
typedef float f32x4  __attribute__((ext_vector_type(4)));

__device__ __forceinline__ unsigned short f2bf(float f) {
    union { float f; unsigned u; } v; v.f = f;
    unsigned r = v.u + 0x7FFFu + ((v.u >> 16) & 1u);
    return (unsigned short)(r >> 16);
}

__device__ __forceinline__ void async_copy16(const void* g, void* l) {
    __builtin_amdgcn_global_load_lds(
        (const __attribute__((address_space(1))) unsigned int*)g,
        (__attribute__((address_space(3))) unsigned int*)l, 16, 0, 0);
}

// ---------------- per-row scale (fp64 for quantization-boundary fidelity) ----------------
__global__ void scale_kernel(const float* __restrict__ w, double* __restrict__ scale) {
    int row = blockIdx.x;
    const float4* wr = (const float4*)(w + (size_t)row * DIN);
    double s = 0.0;
    for (int i = threadIdx.x; i < DIN / 4; i += 256) {
        float4 v = wr[i];
        s += (double)fabsf(v.x) + (double)fabsf(v.y) + (double)fabsf(v.z) + (double)fabsf(v.w);
    }
    for (int o = 32; o > 0; o >>= 1) s += __shfl_down(s, o);
    __shared__ double part[4];
    int wave = threadIdx.x >> 6, lane = threadIdx.x & 63;
    if (lane == 0) part[wave] = s;
    __syncthreads();
    if (threadIdx.x == 0) {
        double m = (part[0] + part[1] + part[2] + part[3]) * (1.0 / DIN);
        scale[row] = fmax(m, 1e-5);
    }
}

// ---------------- build w_eff bf16 ----------------
__global__ void weff_kernel(const float* __restrict__ w, const float* __restrict__ fast,
                            const float* __restrict__ slow, const double* __restrict__ scale,
                            unsigned short* __restrict__ weff) {
    int i4 = blockIdx.x * 256 + threadIdx.x;   // float4 index, 4194304 total
    double sc = scale[i4 >> 10];
    float4 wv = ((const float4*)w)[i4];
    float4 fv = ((const float4*)fast)[i4];
    float4 sv = ((const float4*)slow)[i4];
    ushort4 o;
    o.x = f2bf((float)(fmin(fmax(rint((double)wv.x / sc), -1.0), 1.0) * sc + 0.1 * (double)fv.x + 0.05 * (double)sv.x));
    o.y = f2bf((float)(fmin(fmax(rint((double)wv.y / sc), -1.0), 1.0) * sc + 0.1 * (double)fv.y + 0.05 * (double)sv.y));
    o.z = f2bf((float)(fmin(fmax(rint((double)wv.z / sc), -1.0), 1.0) * sc + 0.1 * (double)fv.z + 0.05 * (double)sv.z));
    o.w = f2bf((float)(fmin(fmax(rint((double)wv.w / sc), -1.0), 1.0) * sc + 0.1 * (double)fv.w + 0.05 * (double)sv.w));
    ((ushort4*)weff)[i4] = o;
}

// ---------------- x -> x_bf16 (row-major) + xT bf16 ----------------
__global__ void transpose_kernel(const float* __restrict__ x, unsigned short* __restrict__ xbf,
                                 unsigned short* __restrict__ xT) {
    __shared__ unsigned short tile[32][33];
    int bi = blockIdx.y, bj = blockIdx.x;
    int tx = threadIdx.x, ty = threadIdx.y;  // (32, 8)
    #pragma unroll
    for (int s = 0; s < 4; ++s) {
        unsigned short b = f2bf(x[(size_t)(bi * 32 + ty + s * 8) * DIN + bj * 32 + tx]);
        tile[ty + s * 8][tx] = b;
        xbf[(size_t)(bi * 32 + ty + s * 8) * DIN + bj * 32 + tx] = b;
    }
    __syncthreads();
    #pragma unroll
    for (int s = 0; s < 4; ++s)
        xT[(size_t)(bj * 32 + ty + s * 8) * NTOK + bi * 32 + tx] = tile[tx][ty + s * 8];
}

// ---------------- GEMM1: y[n,m] = sum_k xbf[n,k]*weff[m,k]; epilogue: y fp32 + relu(y)^T bf16 ----------------
__launch_bounds__(256)
__global__ void gemm1_kernel(const unsigned short* __restrict__ xbf, const unsigned short* __restrict__ weff,
                             float* __restrict__ y, unsigned short* __restrict__ yactT) {
    __shared__ unsigned short smem[16640];           // 33.3 KB: staging (16KB) then 128x130 transpose
    unsigned short* sA = smem;                       // [128][32]
    unsigned short* sB = smem + 4096;                // [128][32]
    int tid = threadIdx.x;
    int wave = tid >> 6, lane = tid & 63, quad = lane >> 4, l16 = lane & 15;
    int waveRow = wave >> 1, waveCol = wave & 1;
    int rowBase = blockIdx.y * 128;                  // n
    int colBase = blockIdx.x * 128;                  // m

    // staging addresses: chunk idx = tid + p*256; row = idx>>2, halves kk = (idx&3)*8
    int srow = tid >> 2, skk = (tid & 3) * 8;

    f32x4 zero = {0.f, 0.f, 0.f, 0.f};
    f32x4 acc[4][4];
    #pragma unroll
    for (int i = 0; i < 4; ++i)
        #pragma unroll
        for (int j = 0; j < 4; ++j) acc[i][j] = zero;

    for (int k0 = 0; k0 < DIN; k0 += 32) {
        #pragma unroll
        for (int p = 0; p < 2; ++p) {                // A: 64 rows per p-round
            async_copy16(xbf + (size_t)(rowBase + srow + p * 64) * DIN + k0 + skk,
                         sA + (tid + p * 256) * 8);
            async_copy16(weff + (size_t)(colBase + srow + p * 64) * DIN + k0 + skk,
                         sB + (tid + p * 256) * 8);
        }
        __syncthreads();
        bf16x8 af[4], bfr[4];
        #pragma unroll
        for (int i = 0; i < 4; ++i)
            af[i] = *(const bf16x8*)(sA + (waveRow * 64 + i * 16 + l16) * 32 + quad * 8);
        #pragma unroll
        for (int j = 0; j < 4; ++j)
            bfr[j] = *(const bf16x8*)(sB + (waveCol * 64 + j * 16 + l16) * 32 + quad * 8);
        #pragma unroll
        for (int i = 0; i < 4; ++i)
            #pragma unroll
            for (int j = 0; j < 4; ++j)
                acc[i][j] = __builtin_amdgcn_mfma_f32_16x16x32_bf16(af[i], bfr[j], acc[i][j], 0, 0, 0);
        __syncthreads();
    }

    // y fp32 store + relu-transpose into LDS
    #pragma unroll
    for (int i = 0; i < 4; ++i) {
        int rl = waveRow * 64 + i * 16 + quad * 4;
        #pragma unroll
        for (int j = 0; j < 4; ++j) {
            int cl = waveCol * 64 + j * 16 + l16;
            #pragma unroll
            for (int r = 0; r < 4; ++r) {
                float v = acc[i][j][r];
                y[(size_t)(rowBase + rl + r) * DOUT + colBase + cl] = v;
                smem[cl * 130 + rl + r] = f2bf(fmaxf(v, 0.0f));
            }
        }
    }
    __syncthreads();
    // coalesced write of yactT[m][n]
    int rowT = tid >> 1, cst = (tid & 1) * 64;
    const unsigned int* l32 = (const unsigned int*)smem;
    int b2 = rowT * 65 + (cst >> 1);
    #pragma unroll
    for (int g = 0; g < 8; ++g) {
        uint4 v;
        v.x = l32[b2 + g * 4 + 0]; v.y = l32[b2 + g * 4 + 1];
        v.z = l32[b2 + g * 4 + 2]; v.w = l32[b2 + g * 4 + 3];
        *(uint4*)(yactT + (size_t)(colBase + rowT) * NTOK + rowBase + cst + g * 8) = v;
    }
}

// ---------------- GEMM2: nf_pre[m,k] = 0.95*fast + 0.05*(sum_n yactT[m,n]*xT[k,n])/4096 ----------------
__launch_bounds__(256)
__global__ void gemm2_kernel(const unsigned short* __restrict__ yactT, const unsigned short* __restrict__ xT,
                             const float* __restrict__ fast, float* __restrict__ outFast,
                             float* __restrict__ norm2) {
    __shared__ unsigned short sA[128 * 32];
    __shared__ unsigned short sB[128 * 32];
    __shared__ float redbuf[4];
    int tid = threadIdx.x;
    int wave = tid >> 6, lane = tid & 63, quad = lane >> 4, l16 = lane & 15;
    int waveRow = wave >> 1, waveCol = wave & 1;
    int rowBase = blockIdx.y * 128;                  // m
    int colBase = blockIdx.x * 128;                  // k

    int srow = tid >> 2, skk = (tid & 3) * 8;

    f32x4 zero = {0.f, 0.f, 0.f, 0.f};
    f32x4 acc[4][4];
    #pragma unroll
    for (int i = 0; i < 4; ++i)
        #pragma unroll
        for (int j = 0; j < 4; ++j) acc[i][j] = zero;

    for (int n0 = 0; n0 < NTOK; n0 += 32) {
        #pragma unroll
        for (int p = 0; p < 2; ++p) {
            async_copy16(yactT + (size_t)(rowBase + srow + p * 64) * NTOK + n0 + skk,
                         sA + (tid + p * 256) * 8);
            async_copy16(xT + (size_t)(colBase + srow + p * 64) * NTOK + n0 + skk,
                         sB + (tid + p * 256) * 8);
        }
        __syncthreads();
        bf16x8 af[4], bfr[4];
        #pragma unroll
        for (int i = 0; i < 4; ++i)
            af[i] = *(const bf16x8*)(sA + (waveRow * 64 + i * 16 + l16) * 32 + quad * 8);
        #pragma unroll
        for (int j = 0; j < 4; ++j)
            bfr[j] = *(const bf16x8*)(sB + (waveCol * 64 + j * 16 + l16) * 32 + quad * 8);
        #pragma unroll
        for (int i = 0; i < 4; ++i)
            #pragma unroll
            for (int j = 0; j < 4; ++j)
                acc[i][j] = __builtin_amdgcn_mfma_f32_16x16x32_bf16(af[i], bfr[j], acc[i][j], 0, 0, 0);
        __syncthreads();
    }

    float lsum = 0.f;
    #pragma unroll
    for (int i = 0; i < 4; ++i) {
        int rg = rowBase + waveRow * 64 + i * 16 + quad * 4;
        #pragma unroll
        for (int j = 0; j < 4; ++j) {
            int cg = colBase + waveCol * 64 + j * 16 + l16;
            #pragma unroll
            for (int r = 0; r < 4; ++r) {
                float d = acc[i][j][r] * (1.0f / 4096.0f);
                float nf = 0.95f * fast[(size_t)(rg + r) * DIN + cg] + 0.05f * d;
                outFast[(size_t)(rg + r) * DIN + cg] = nf;
                lsum += nf * nf;
            }
        }
    }
    for (int o = 32; o > 0; o >>= 1) lsum += __shfl_down(lsum, o);
    if (lane == 0) redbuf[wave] = lsum;
    __syncthreads();
    if (tid == 0) atomicAdd(norm2, redbuf[0] + redbuf[1] + redbuf[2] + redbuf[3]);
}

// ---------------- finalize: homeostatic rescale + slow update ----------------
__global__ void finalize_kernel(const float* __restrict__ slow, float* __restrict__ outFast,
                                float* __restrict__ outSlow, const float* __restrict__ norm2) {
    float n = sqrtf(*norm2);
    float s = (n > 5.0f) ? 5.0f / (n + 1e-6f) : 1.0f;
    int i = blockIdx.x * 256 + threadIdx.x;          // float4 index
    float4 f = ((const float4*)outFast)[i];
    f.x *= s; f.y *= s; f.z *= s; f.w *= s;
    ((float4*)outFast)[i] = f;
    float4 sl = ((const float4*)slow)[i];
    float4 o;
    o.x = 0.99f * sl.x + 0.01f * f.x;
    o.y = 0.99f * sl.y + 0.01f * f.y;
    o.z = 0.99f * sl.z + 0.01f * f.z;
    o.w = 0.99f * sl.w + 0.01f * f.w;
    ((float4*)outSlow)[i] = o;
}

extern "C" void kernel_launch(void* const* d_in, const int* in_sizes, int n_in,
                              void* d_out, int out_size, void* d_ws, size_t ws_size,
                              hipStream_t stream) {
    const float* x    = (const float*)d_in[0];
    const float* w    = (const float*)d_in[1];
    const float* fast = (const float*)d_in[2];
    const float* slow = (const float*)d_in[3];
    float* y       = (float*)d_out;
    float* outFast = y + (size_t)NTOK * DOUT;
    float* outSlow = outFast + (size_t)DOUT * DIN;

    char* ws = (char*)d_ws;
    double* scale = (double*)ws;                               // 32 KB
    float* norm2  = (float*)(ws + 32768);                      // 4 B (+pad)
    unsigned short* weff  = (unsigned short*)(ws + 32768 + 256);
    unsigned short* xbf   = weff + (size_t)DOUT * DIN;
    unsigned short* xT    = xbf + (size_t)NTOK * DIN;
    unsigned short* yactT = xT + (size_t)DIN * NTOK;
    // total ws use: ~33 KB + 4 * 33.55 MB ≈ 134 MB

    hipMemsetAsync(norm2, 0, sizeof(float), stream);
    scale_kernel<<<4096, 256, 0, stream>>>(w, scale);
    weff_kernel<<<16384, 256, 0, stream>>>(w, fast, slow, scale, weff);
    transpose_kernel<<<dim3(128, 128), dim3(32, 8), 0, stream>>>(x, xbf, xT);
    gemm1_kernel<<<dim3(32, 32), 256, 0, stream>>>(xbf, weff, y, yactT);
    gemm2_kernel<<<dim3(32, 32), 256, 0, stream>>>(yactT, xT, fast, outFast, norm2);
    finalize_kernel<<<16384, 256, 0, stream>>>(slow, outFast, outSlow, norm2);
}